// Round 2
// baseline (5860.234 us; speedup 1.0000x reference)
//
#include <hip/hip_runtime.h>
#include <hip/hip_bf16.h>

#define HEADS 4
#define D_K 32
#define IN_FEAT 256
#define OUT_TOTAL (HEADS * D_K)   // 128
#define BN 32                      // nodes per projection block

// ---- monotone float<->uint encoding for atomicMax on f32 ----
__device__ __forceinline__ unsigned f2ord(float f) {
    unsigned b = __float_as_uint(f);
    return (b & 0x80000000u) ? ~b : (b | 0x80000000u);
}
__device__ __forceinline__ float ord2f(unsigned u) {
    unsigned b = (u & 0x80000000u) ? (u & 0x7FFFFFFFu) : ~u;
    return __uint_as_float(b);
}

// ---- kernel 1: Q,K,V = x @ Wq/Wk/Wv ----
// grid = ceil(n/BN) blocks, 384 threads: thread t owns column (t&127) of
// matrix (t>>7) in {Wq,Wk,Wv}. x-tile staged in LDS, broadcast float4 reads.
__global__ __launch_bounds__(384) void proj_kernel(
    const float* __restrict__ x,
    const float* __restrict__ Wq, const float* __restrict__ Wk,
    const float* __restrict__ Wv,
    float* __restrict__ Q, float* __restrict__ K, float* __restrict__ V,
    int n_nodes)
{
    __shared__ float xs[BN][IN_FEAT];
    const int node0 = blockIdx.x * BN;
    const int t = threadIdx.x;

    for (int i = t; i < BN * IN_FEAT; i += 384) {
        int n = i >> 8, k = i & 255;
        int node = node0 + n;
        xs[n][k] = (node < n_nodes) ? x[(size_t)node * IN_FEAT + k] : 0.f;
    }
    __syncthreads();

    const int m = t >> 7;        // 0=Q,1=K,2=V
    const int c = t & 127;
    const float* __restrict__ W = (m == 0) ? Wq : (m == 1) ? Wk : Wv;

    float acc[BN];
#pragma unroll
    for (int n = 0; n < BN; n++) acc[n] = 0.f;

    for (int k4 = 0; k4 < IN_FEAT; k4 += 4) {
        float w0 = W[(k4 + 0) * OUT_TOTAL + c];
        float w1 = W[(k4 + 1) * OUT_TOTAL + c];
        float w2 = W[(k4 + 2) * OUT_TOTAL + c];
        float w3 = W[(k4 + 3) * OUT_TOTAL + c];
#pragma unroll
        for (int n = 0; n < BN; n++) {
            float4 xv = *reinterpret_cast<const float4*>(&xs[n][k4]);
            acc[n] = fmaf(xv.x, w0, acc[n]);
            acc[n] = fmaf(xv.y, w1, acc[n]);
            acc[n] = fmaf(xv.z, w2, acc[n]);
            acc[n] = fmaf(xv.w, w3, acc[n]);
        }
    }

    float* __restrict__ O = (m == 0) ? Q : (m == 1) ? K : V;
#pragma unroll
    for (int n = 0; n < BN; n++) {
        int node = node0 + n;
        if (node < n_nodes) O[(size_t)node * OUT_TOTAL + c] = acc[n];
    }
}

// ---- kernel 2: per-(edge,head) scores + segment max ----
__global__ __launch_bounds__(256) void edge_scores_kernel(
    const float* __restrict__ Q, const float* __restrict__ K,
    const int* __restrict__ row, const int* __restrict__ col,
    float* __restrict__ scores, unsigned* __restrict__ smax, int n_edges)
{
    int idx = blockIdx.x * 256 + threadIdx.x;
    if (idx >= n_edges * HEADS) return;
    int e = idx >> 2, h = idx & 3;
    int r = row[e], cn = col[e];

    const float4* q = reinterpret_cast<const float4*>(&Q[(size_t)r * OUT_TOTAL + h * D_K]);
    const float4* k = reinterpret_cast<const float4*>(&K[(size_t)cn * OUT_TOTAL + h * D_K]);
    float s = 0.f;
#pragma unroll
    for (int i = 0; i < D_K / 4; i++) {
        float4 a = q[i], b = k[i];
        s += a.x * b.x + a.y * b.y + a.z * b.z + a.w * b.w;
    }
    s *= 0.17677669529663689f;   // 1/sqrt(32)
    scores[idx] = s;
    atomicMax(&smax[r * HEADS + h], f2ord(s));
}

// ---- kernel 3: ex = exp(s - max), segment sum (in-place over scores) ----
__global__ __launch_bounds__(256) void edge_exp_kernel(
    float* __restrict__ ex, const int* __restrict__ row,
    const unsigned* __restrict__ smax, float* __restrict__ ssum, int n_edges)
{
    int idx = blockIdx.x * 256 + threadIdx.x;
    if (idx >= n_edges * HEADS) return;
    int e = idx >> 2, h = idx & 3;
    int r = row[e];
    float m = ord2f(smax[r * HEADS + h]);
    float v = expf(ex[idx] - m);
    ex[idx] = v;
    unsafeAtomicAdd(&ssum[r * HEADS + h], v);
}

// ---- kernel 4: out[row] += (ex/ssum) * V[col] ----
__global__ __launch_bounds__(256) void edge_scatter_kernel(
    const float* __restrict__ ex, const float* __restrict__ ssum,
    const float* __restrict__ V,
    const int* __restrict__ row, const int* __restrict__ col,
    float* __restrict__ out, int n_edges)
{
    int idx = blockIdx.x * 256 + threadIdx.x;
    if (idx >= n_edges * HEADS) return;
    int e = idx >> 2, h = idx & 3;
    int r = row[e], cn = col[e];
    float alpha = ex[idx] / ssum[r * HEADS + h];

    const float4* v = reinterpret_cast<const float4*>(&V[(size_t)cn * OUT_TOTAL + h * D_K]);
    float* o = &out[(size_t)r * OUT_TOTAL + h * D_K];
#pragma unroll
    for (int i = 0; i < D_K / 4; i++) {
        float4 vv = v[i];
        unsafeAtomicAdd(&o[i * 4 + 0], alpha * vv.x);
        unsafeAtomicAdd(&o[i * 4 + 1], alpha * vv.y);
        unsafeAtomicAdd(&o[i * 4 + 2], alpha * vv.z);
        unsafeAtomicAdd(&o[i * 4 + 3], alpha * vv.w);
    }
}

extern "C" void kernel_launch(void* const* d_in, const int* in_sizes, int n_in,
                              void* d_out, int out_size, void* d_ws, size_t ws_size,
                              hipStream_t stream)
{
    const float* x  = (const float*)d_in[0];
    const float* Wq = (const float*)d_in[1];
    const float* Wk = (const float*)d_in[2];
    const float* Wv = (const float*)d_in[3];
    const int*   ei = (const int*)d_in[4];
    float* out = (float*)d_out;

    const int n_nodes = in_sizes[0] / IN_FEAT;   // 50000
    const int n_edges = in_sizes[4] / 2;         // 800000
    const int* row = ei;
    const int* col = ei + n_edges;

    char* ws = (char*)d_ws;
    float* Q = (float*)ws;          ws += (size_t)n_nodes * OUT_TOTAL * sizeof(float);
    float* K = (float*)ws;          ws += (size_t)n_nodes * OUT_TOTAL * sizeof(float);
    float* V = (float*)ws;          ws += (size_t)n_nodes * OUT_TOTAL * sizeof(float);
    unsigned* smax = (unsigned*)ws; ws += (size_t)n_nodes * HEADS * sizeof(unsigned);
    float* ssum = (float*)ws;       ws += (size_t)n_nodes * HEADS * sizeof(float);
    float* ex = (float*)ws;         ws += (size_t)n_edges * HEADS * sizeof(float);

    (void)hipMemsetAsync(out, 0, (size_t)out_size * sizeof(float), stream);
    (void)hipMemsetAsync(smax, 0, (size_t)n_nodes * HEADS * sizeof(unsigned), stream);
    (void)hipMemsetAsync(ssum, 0, (size_t)n_nodes * HEADS * sizeof(float), stream);

    proj_kernel<<<(n_nodes + BN - 1) / BN, 384, 0, stream>>>(
        x, Wq, Wk, Wv, Q, K, V, n_nodes);

    int eh = n_edges * HEADS;
    int eb = (eh + 255) / 256;
    edge_scores_kernel<<<eb, 256, 0, stream>>>(Q, K, row, col, ex, smax, n_edges);
    edge_exp_kernel<<<eb, 256, 0, stream>>>(ex, row, smax, ssum, n_edges);
    edge_scatter_kernel<<<eb, 256, 0, stream>>>(ex, ssum, V, row, col, out, n_edges);
}

// Round 3
// 559.908 us; speedup vs baseline: 10.4664x; 10.4664x over previous
//
#include <hip/hip_runtime.h>
#include <hip/hip_bf16.h>

#define HEADS 4
#define D_K 32
#define IN_FEAT 256
#define OUT_TOTAL (HEADS * D_K)   // 128
#define BN 32                      // nodes per projection block
#define NEG_BIG -3.0e38f

// ---- kernel 1: Q,K,V = x @ Wq/Wk/Wv ----
__global__ __launch_bounds__(384) void proj_kernel(
    const float* __restrict__ x,
    const float* __restrict__ Wq, const float* __restrict__ Wk,
    const float* __restrict__ Wv,
    float* __restrict__ Q, float* __restrict__ K, float* __restrict__ V,
    int n_nodes)
{
    __shared__ float xs[BN][IN_FEAT];
    const int node0 = blockIdx.x * BN;
    const int t = threadIdx.x;

    for (int i = t; i < BN * IN_FEAT; i += 384) {
        int n = i >> 8, k = i & 255;
        int node = node0 + n;
        xs[n][k] = (node < n_nodes) ? x[(size_t)node * IN_FEAT + k] : 0.f;
    }
    __syncthreads();

    const int m = t >> 7;        // 0=Q,1=K,2=V
    const int c = t & 127;
    const float* __restrict__ W = (m == 0) ? Wq : (m == 1) ? Wk : Wv;

    float acc[BN];
#pragma unroll
    for (int n = 0; n < BN; n++) acc[n] = 0.f;

    for (int k4 = 0; k4 < IN_FEAT; k4 += 4) {
        float w0 = W[(k4 + 0) * OUT_TOTAL + c];
        float w1 = W[(k4 + 1) * OUT_TOTAL + c];
        float w2 = W[(k4 + 2) * OUT_TOTAL + c];
        float w3 = W[(k4 + 3) * OUT_TOTAL + c];
#pragma unroll
        for (int n = 0; n < BN; n++) {
            float4 xv = *reinterpret_cast<const float4*>(&xs[n][k4]);
            acc[n] = fmaf(xv.x, w0, acc[n]);
            acc[n] = fmaf(xv.y, w1, acc[n]);
            acc[n] = fmaf(xv.z, w2, acc[n]);
            acc[n] = fmaf(xv.w, w3, acc[n]);
        }
    }

    float* __restrict__ O = (m == 0) ? Q : (m == 1) ? K : V;
#pragma unroll
    for (int n = 0; n < BN; n++) {
        int node = node0 + n;
        if (node < n_nodes) O[(size_t)node * OUT_TOTAL + c] = acc[n];
    }
}

// ---- CSR build: degree count ----
__global__ __launch_bounds__(256) void deg_kernel(
    const int* __restrict__ row, int* __restrict__ deg, int n_edges)
{
    int e = blockIdx.x * 256 + threadIdx.x;
    if (e < n_edges) atomicAdd(&deg[row[e]], 1);
}

// ---- CSR build: single-block exclusive scan (n=50000, 1024 threads) ----
__global__ __launch_bounds__(1024) void scan_kernel(
    const int* __restrict__ deg, int* __restrict__ off, int n)
{
    __shared__ int tmp[1024];
    __shared__ int carry_s;
    int t = threadIdx.x;
    if (t == 0) carry_s = 0;
    __syncthreads();
    for (int base = 0; base < n; base += 1024) {
        int v = (base + t < n) ? deg[base + t] : 0;
        tmp[t] = v;
        __syncthreads();
#pragma unroll
        for (int s = 1; s < 1024; s <<= 1) {
            int add = (t >= s) ? tmp[t - s] : 0;
            __syncthreads();
            tmp[t] += add;
            __syncthreads();
        }
        int incl = tmp[t];
        int carry = carry_s;
        if (base + t < n) off[base + t] = carry + incl - v;
        __syncthreads();
        if (t == 0) carry_s = carry + tmp[1023];
        __syncthreads();
    }
    if (t == 0) off[n] = carry_s;
}

// ---- CSR build: scatter col indices into buckets ----
__global__ __launch_bounds__(256) void fill_kernel(
    const int* __restrict__ row, const int* __restrict__ col,
    const int* __restrict__ off, int* __restrict__ cursor,
    int* __restrict__ csr_col, int n_edges)
{
    int e = blockIdx.x * 256 + threadIdx.x;
    if (e < n_edges) {
        int r = row[e];
        int pos = atomicAdd(&cursor[r], 1);
        csr_col[off[r] + pos] = col[e];
    }
}

// ---- fused per-node attention: one wave per node ----
// lane l: head = l&3, edge slot = l>>2 (16 slots). Online softmax across
// chunks of 16 edges; head-group reductions via __shfl_xor (4,8,16,32).
__global__ __launch_bounds__(256) void node_attn_kernel(
    const float* __restrict__ Q, const float* __restrict__ K,
    const float* __restrict__ V,
    const int* __restrict__ off, const int* __restrict__ csr_col,
    float* __restrict__ out, int n_nodes)
{
    int wave = (blockIdx.x * 256 + threadIdx.x) >> 6;
    if (wave >= n_nodes) return;
    const int node = wave;
    const int lane = threadIdx.x & 63;
    const int h = lane & 3;
    const int slot = lane >> 2;

    const int e0 = off[node];
    const int deg = off[node + 1] - e0;

    float4 q[8];
    const float4* qp = reinterpret_cast<const float4*>(&Q[(size_t)node * OUT_TOTAL + h * D_K]);
#pragma unroll
    for (int i = 0; i < 8; i++) q[i] = qp[i];

    float m = NEG_BIG;
    float ssum = 0.f;
    float acc[D_K];
#pragma unroll
    for (int i = 0; i < D_K; i++) acc[i] = 0.f;

    for (int base = 0; base < deg; base += 16) {
        int ei = base + slot;
        bool act = (ei < deg);
        int cn = act ? csr_col[e0 + ei] : 0;

        float s = NEG_BIG;
        if (act) {
            const float4* kp = reinterpret_cast<const float4*>(&K[(size_t)cn * OUT_TOTAL + h * D_K]);
            float d = 0.f;
#pragma unroll
            for (int i = 0; i < 8; i++) {
                float4 kv = kp[i];
                d += q[i].x * kv.x + q[i].y * kv.y + q[i].z * kv.z + q[i].w * kv.w;
            }
            s = d * 0.17677669529663689f;   // 1/sqrt(32)
        }

        // head-group max (lanes sharing lane&3)
        float cmax = s;
        cmax = fmaxf(cmax, __shfl_xor(cmax, 4));
        cmax = fmaxf(cmax, __shfl_xor(cmax, 8));
        cmax = fmaxf(cmax, __shfl_xor(cmax, 16));
        cmax = fmaxf(cmax, __shfl_xor(cmax, 32));
        float m_new = fmaxf(m, cmax);
        float scale = __expf(m - m_new);     // finite sentinel: underflows to 0, no NaN
        ssum *= scale;
#pragma unroll
        for (int i = 0; i < D_K; i++) acc[i] *= scale;
        m = m_new;

        float w = act ? __expf(s - m_new) : 0.f;
        ssum += w;

        if (act) {
            const float4* vp = reinterpret_cast<const float4*>(&V[(size_t)cn * OUT_TOTAL + h * D_K]);
#pragma unroll
            for (int i = 0; i < 8; i++) {
                float4 vv = vp[i];
                acc[i * 4 + 0] = fmaf(w, vv.x, acc[i * 4 + 0]);
                acc[i * 4 + 1] = fmaf(w, vv.y, acc[i * 4 + 1]);
                acc[i * 4 + 2] = fmaf(w, vv.z, acc[i * 4 + 2]);
                acc[i * 4 + 3] = fmaf(w, vv.w, acc[i * 4 + 3]);
            }
        }
    }

    // butterfly reduce across the 16-lane head group
    ssum += __shfl_xor(ssum, 4);
    ssum += __shfl_xor(ssum, 8);
    ssum += __shfl_xor(ssum, 16);
    ssum += __shfl_xor(ssum, 32);
#pragma unroll
    for (int i = 0; i < D_K; i++) {
        acc[i] += __shfl_xor(acc[i], 4);
        acc[i] += __shfl_xor(acc[i], 8);
        acc[i] += __shfl_xor(acc[i], 16);
        acc[i] += __shfl_xor(acc[i], 32);
    }

    float inv = (ssum > 0.f) ? 1.f / ssum : 0.f;
    float2 w2;
    w2.x = acc[slot * 2 + 0] * inv;
    w2.y = acc[slot * 2 + 1] * inv;
    *reinterpret_cast<float2*>(&out[(size_t)node * OUT_TOTAL + h * D_K + slot * 2]) = w2;
}

extern "C" void kernel_launch(void* const* d_in, const int* in_sizes, int n_in,
                              void* d_out, int out_size, void* d_ws, size_t ws_size,
                              hipStream_t stream)
{
    const float* x  = (const float*)d_in[0];
    const float* Wq = (const float*)d_in[1];
    const float* Wk = (const float*)d_in[2];
    const float* Wv = (const float*)d_in[3];
    const int*   ei = (const int*)d_in[4];
    float* out = (float*)d_out;

    const int n_nodes = in_sizes[0] / IN_FEAT;   // 50000
    const int n_edges = in_sizes[4] / 2;         // 800000
    const int* row = ei;
    const int* col = ei + n_edges;

    char* ws = (char*)d_ws;
    float* Q = (float*)ws;        ws += (size_t)n_nodes * OUT_TOTAL * sizeof(float);
    float* K = (float*)ws;        ws += (size_t)n_nodes * OUT_TOTAL * sizeof(float);
    float* V = (float*)ws;        ws += (size_t)n_nodes * OUT_TOTAL * sizeof(float);
    int* deg = (int*)ws;          ws += (size_t)n_nodes * sizeof(int);
    int* off = (int*)ws;          ws += (size_t)(n_nodes + 1) * sizeof(int);
    int* cursor = (int*)ws;       ws += (size_t)n_nodes * sizeof(int);
    int* csr_col = (int*)ws;      ws += (size_t)n_edges * sizeof(int);

    (void)hipMemsetAsync(deg, 0, (size_t)n_nodes * sizeof(int), stream);
    (void)hipMemsetAsync(cursor, 0, (size_t)n_nodes * sizeof(int), stream);

    proj_kernel<<<(n_nodes + BN - 1) / BN, 384, 0, stream>>>(
        x, Wq, Wk, Wv, Q, K, V, n_nodes);

    int eb = (n_edges + 255) / 256;
    deg_kernel<<<eb, 256, 0, stream>>>(row, deg, n_edges);
    scan_kernel<<<1, 1024, 0, stream>>>(deg, off, n_nodes);
    fill_kernel<<<eb, 256, 0, stream>>>(row, col, off, cursor, csr_col, n_edges);

    int waves_per_block = 4;  // 256 threads
    int nb = (n_nodes + waves_per_block - 1) / waves_per_block;
    node_attn_kernel<<<nb, 256, 0, stream>>>(Q, K, V, off, csr_col, out, n_nodes);
}

// Round 4
// 430.914 us; speedup vs baseline: 13.5995x; 1.2993x over previous
//
#include <hip/hip_runtime.h>
#include <hip/hip_bf16.h>

#define HEADS 4
#define D_K 32
#define IN_FEAT 256
#define OUT_TOTAL (HEADS * D_K)   // 128
#define NEG_BIG -3.0e38f

typedef __attribute__((ext_vector_type(8))) short bf16x8;
typedef __attribute__((ext_vector_type(4))) float f32x4;

// f32 -> bf16 round-to-nearest-even (finite inputs)
__device__ __forceinline__ unsigned short f2bf(float f) {
    unsigned u = __float_as_uint(f);
    u += 0x7fffu + ((u >> 16) & 1u);
    return (unsigned short)(u >> 16);
}

// ---- pack W into transposed bf16: wt[m][col][k] = bf16(W_m[k][col]) ----
__global__ __launch_bounds__(256) void pack_w_kernel(
    const float* __restrict__ Wq, const float* __restrict__ Wk,
    const float* __restrict__ Wv, unsigned short* __restrict__ wt)
{
    int idx = blockIdx.x * 256 + threadIdx.x;     // over 3*128*256
    if (idx >= 3 * OUT_TOTAL * IN_FEAT) return;
    int k = idx & 255;
    int c = (idx >> 8) & 127;
    int m = idx >> 15;
    const float* W = (m == 0) ? Wq : (m == 1) ? Wk : Wv;
    wt[idx] = f2bf(W[k * OUT_TOTAL + c]);
}

// ---- MFMA projection: Q,K,V = x @ Wq/Wk/Wv ----
// block = 4 waves x 16 rows = 64 rows. Wave computes 16x128 per matrix.
// A cast f32->bf16 in-register; B from pre-packed wt (16B frags).
__global__ __launch_bounds__(256) void proj_mfma_kernel(
    const float* __restrict__ x, const unsigned short* __restrict__ wt,
    float* __restrict__ Q, float* __restrict__ K, float* __restrict__ V,
    int n_nodes)
{
    const int w = threadIdx.x >> 6;
    const int l = threadIdx.x & 63;
    const int node0 = blockIdx.x * 64 + w * 16;
    if (node0 >= n_nodes) return;                 // n_nodes % 16 == 0

    const int kc = (l >> 4) * 8;                  // k-chunk within 32
    const int row = node0 + (l & 15);

    // A fragments: 8 k-steps x 8 bf16
    bf16x8 a[8];
    const float* xr = x + (size_t)row * IN_FEAT + kc;
#pragma unroll
    for (int ks = 0; ks < 8; ks++) {
        float4 f0 = *reinterpret_cast<const float4*>(xr + ks * 32);
        float4 f1 = *reinterpret_cast<const float4*>(xr + ks * 32 + 4);
        bf16x8 av;
        av[0] = (short)f2bf(f0.x); av[1] = (short)f2bf(f0.y);
        av[2] = (short)f2bf(f0.z); av[3] = (short)f2bf(f0.w);
        av[4] = (short)f2bf(f1.x); av[5] = (short)f2bf(f1.y);
        av[6] = (short)f2bf(f1.z); av[7] = (short)f2bf(f1.w);
        a[ks] = av;
    }

    const int r0 = node0 + (l >> 4) * 4;
#pragma unroll
    for (int m = 0; m < 3; m++) {
        float* __restrict__ O = (m == 0) ? Q : (m == 1) ? K : V;
        const unsigned short* wtm = wt + (size_t)m * OUT_TOTAL * IN_FEAT;
#pragma unroll
        for (int nf = 0; nf < 8; nf++) {
            int col = nf * 16 + (l & 15);
            const unsigned short* wcol = wtm + (size_t)col * IN_FEAT + kc;
            f32x4 acc = {0.f, 0.f, 0.f, 0.f};
#pragma unroll
            for (int ks = 0; ks < 8; ks++) {
                bf16x8 b = *reinterpret_cast<const bf16x8*>(wcol + ks * 32);
                acc = __builtin_amdgcn_mfma_f32_16x16x32_bf16(a[ks], b, acc, 0, 0, 0);
            }
#pragma unroll
            for (int j = 0; j < 4; j++)
                O[(size_t)(r0 + j) * OUT_TOTAL + col] = acc[j];
        }
    }
}

// ---- CSR build: degree count ----
__global__ __launch_bounds__(256) void deg_kernel(
    const int* __restrict__ row, int* __restrict__ deg, int n_edges)
{
    int e = blockIdx.x * 256 + threadIdx.x;
    if (e < n_edges) atomicAdd(&deg[row[e]], 1);
}

// ---- CSR build: single-block chunked exclusive scan ----
__global__ __launch_bounds__(1024) void scan_kernel(
    const int* __restrict__ deg, int* __restrict__ off, int n)
{
    const int T = 1024;
    int t = threadIdx.x;
    int chunk = (n + T - 1) / T;
    int b0 = t * chunk;
    int b1 = min(b0 + chunk, n);
    int s = 0;
    for (int i = b0; i < b1; i++) s += deg[i];

    __shared__ int tmp[T];
    tmp[t] = s;
    __syncthreads();
    for (int st = 1; st < T; st <<= 1) {
        int add = (t >= st) ? tmp[t - st] : 0;
        __syncthreads();
        tmp[t] += add;
        __syncthreads();
    }
    int excl = tmp[t] - s;
    for (int i = b0; i < b1; i++) { off[i] = excl; excl += deg[i]; }
    if (t == T - 1) off[n] = tmp[T - 1];
}

// ---- CSR build: scatter col indices into buckets ----
__global__ __launch_bounds__(256) void fill_kernel(
    const int* __restrict__ row, const int* __restrict__ col,
    const int* __restrict__ off, int* __restrict__ cursor,
    int* __restrict__ csr_col, int n_edges)
{
    int e = blockIdx.x * 256 + threadIdx.x;
    if (e < n_edges) {
        int r = row[e];
        int pos = atomicAdd(&cursor[r], 1);
        csr_col[off[r] + pos] = col[e];
    }
}

// ---- fused per-node attention: one wave per node ----
__global__ __launch_bounds__(256) void node_attn_kernel(
    const float* __restrict__ Q, const float* __restrict__ K,
    const float* __restrict__ V,
    const int* __restrict__ off, const int* __restrict__ csr_col,
    float* __restrict__ out, int n_nodes)
{
    int wave = (blockIdx.x * 256 + threadIdx.x) >> 6;
    if (wave >= n_nodes) return;
    const int node = wave;
    const int lane = threadIdx.x & 63;
    const int h = lane & 3;
    const int slot = lane >> 2;

    const int e0 = off[node];
    const int deg = off[node + 1] - e0;

    float4 q[8];
    const float4* qp = reinterpret_cast<const float4*>(&Q[(size_t)node * OUT_TOTAL + h * D_K]);
#pragma unroll
    for (int i = 0; i < 8; i++) q[i] = qp[i];

    float m = NEG_BIG;
    float ssum = 0.f;
    float acc[D_K];
#pragma unroll
    for (int i = 0; i < D_K; i++) acc[i] = 0.f;

    for (int base = 0; base < deg; base += 16) {
        int ei = base + slot;
        bool act = (ei < deg);
        int cn = act ? csr_col[e0 + ei] : 0;

        float s = NEG_BIG;
        if (act) {
            const float4* kp = reinterpret_cast<const float4*>(&K[(size_t)cn * OUT_TOTAL + h * D_K]);
            float d = 0.f;
#pragma unroll
            for (int i = 0; i < 8; i++) {
                float4 kv = kp[i];
                d += q[i].x * kv.x + q[i].y * kv.y + q[i].z * kv.z + q[i].w * kv.w;
            }
            s = d * 0.17677669529663689f;   // 1/sqrt(32)
        }

        float cmax = s;
        cmax = fmaxf(cmax, __shfl_xor(cmax, 4));
        cmax = fmaxf(cmax, __shfl_xor(cmax, 8));
        cmax = fmaxf(cmax, __shfl_xor(cmax, 16));
        cmax = fmaxf(cmax, __shfl_xor(cmax, 32));
        float m_new = fmaxf(m, cmax);
        float scale = __expf(m - m_new);
        ssum *= scale;
#pragma unroll
        for (int i = 0; i < D_K; i++) acc[i] *= scale;
        m = m_new;

        float wgt = act ? __expf(s - m_new) : 0.f;
        ssum += wgt;

        if (act) {
            const float4* vp = reinterpret_cast<const float4*>(&V[(size_t)cn * OUT_TOTAL + h * D_K]);
#pragma unroll
            for (int i = 0; i < 8; i++) {
                float4 vv = vp[i];
                acc[i * 4 + 0] = fmaf(wgt, vv.x, acc[i * 4 + 0]);
                acc[i * 4 + 1] = fmaf(wgt, vv.y, acc[i * 4 + 1]);
                acc[i * 4 + 2] = fmaf(wgt, vv.z, acc[i * 4 + 2]);
                acc[i * 4 + 3] = fmaf(wgt, vv.w, acc[i * 4 + 3]);
            }
        }
    }

    ssum += __shfl_xor(ssum, 4);
    ssum += __shfl_xor(ssum, 8);
    ssum += __shfl_xor(ssum, 16);
    ssum += __shfl_xor(ssum, 32);
#pragma unroll
    for (int i = 0; i < D_K; i++) {
        acc[i] += __shfl_xor(acc[i], 4);
        acc[i] += __shfl_xor(acc[i], 8);
        acc[i] += __shfl_xor(acc[i], 16);
        acc[i] += __shfl_xor(acc[i], 32);
    }

    float inv = (ssum > 0.f) ? 1.f / ssum : 0.f;
    float2 w2;
    w2.x = acc[slot * 2 + 0] * inv;
    w2.y = acc[slot * 2 + 1] * inv;
    *reinterpret_cast<float2*>(&out[(size_t)node * OUT_TOTAL + h * D_K + slot * 2]) = w2;
}

extern "C" void kernel_launch(void* const* d_in, const int* in_sizes, int n_in,
                              void* d_out, int out_size, void* d_ws, size_t ws_size,
                              hipStream_t stream)
{
    const float* x  = (const float*)d_in[0];
    const float* Wq = (const float*)d_in[1];
    const float* Wk = (const float*)d_in[2];
    const float* Wv = (const float*)d_in[3];
    const int*   ei = (const int*)d_in[4];
    float* out = (float*)d_out;

    const int n_nodes = in_sizes[0] / IN_FEAT;   // 50000
    const int n_edges = in_sizes[4] / 2;         // 800000
    const int* row = ei;
    const int* col = ei + n_edges;

    char* ws = (char*)d_ws;
    float* Q = (float*)ws;              ws += (size_t)n_nodes * OUT_TOTAL * sizeof(float);
    float* K = (float*)ws;              ws += (size_t)n_nodes * OUT_TOTAL * sizeof(float);
    float* V = (float*)ws;              ws += (size_t)n_nodes * OUT_TOTAL * sizeof(float);
    unsigned short* wt = (unsigned short*)ws;
                                        ws += (size_t)3 * OUT_TOTAL * IN_FEAT * sizeof(unsigned short);
    int* deg = (int*)ws;                ws += (size_t)n_nodes * sizeof(int);
    int* off = (int*)ws;                ws += (size_t)(n_nodes + 1) * sizeof(int);
    int* cursor = (int*)ws;             ws += (size_t)n_nodes * sizeof(int);
    int* csr_col = (int*)ws;            ws += (size_t)n_edges * sizeof(int);

    (void)hipMemsetAsync(deg, 0, (size_t)n_nodes * sizeof(int), stream);
    (void)hipMemsetAsync(cursor, 0, (size_t)n_nodes * sizeof(int), stream);

    pack_w_kernel<<<(3 * OUT_TOTAL * IN_FEAT + 255) / 256, 256, 0, stream>>>(Wq, Wk, Wv, wt);
    proj_mfma_kernel<<<(n_nodes + 63) / 64, 256, 0, stream>>>(x, wt, Q, K, V, n_nodes);

    int eb = (n_edges + 255) / 256;
    deg_kernel<<<eb, 256, 0, stream>>>(row, deg, n_edges);
    scan_kernel<<<1, 1024, 0, stream>>>(deg, off, n_nodes);
    fill_kernel<<<eb, 256, 0, stream>>>(row, col, off, cursor, csr_col, n_edges);

    node_attn_kernel<<<(n_nodes + 3) / 4, 256, 0, stream>>>(Q, K, V, off, csr_col, out, n_nodes);
}

// Round 5
// 349.602 us; speedup vs baseline: 16.7626x; 1.2326x over previous
//
#include <hip/hip_runtime.h>
#include <hip/hip_bf16.h>

#define HEADS 4
#define D_K 32
#define IN_FEAT 256
#define OUT_TOTAL (HEADS * D_K)   // 128
#define NEG_BIG -3.0e38f

typedef __attribute__((ext_vector_type(8))) short bf16x8;
typedef __attribute__((ext_vector_type(4))) float f32x4;

// f32 -> bf16 round-to-nearest-even (finite inputs)
__device__ __forceinline__ unsigned short f2bf(float f) {
    unsigned u = __float_as_uint(f);
    u += 0x7fffu + ((u >> 16) & 1u);
    return (unsigned short)(u >> 16);
}
__device__ __forceinline__ float bf2f(unsigned short u) {
    return __uint_as_float(((unsigned)u) << 16);
}

// ---- pack W into transposed bf16: wt[m][col][k] = bf16(W_m[k][col]) ----
__global__ __launch_bounds__(256) void pack_w_kernel(
    const float* __restrict__ Wq, const float* __restrict__ Wk,
    const float* __restrict__ Wv, unsigned short* __restrict__ wt)
{
    int idx = blockIdx.x * 256 + threadIdx.x;     // over 3*128*256
    if (idx >= 3 * OUT_TOTAL * IN_FEAT) return;
    int k = idx & 255;
    int c = (idx >> 8) & 127;
    int m = idx >> 15;
    const float* W = (m == 0) ? Wq : (m == 1) ? Wk : Wv;
    wt[idx] = f2bf(W[k * OUT_TOTAL + c]);
}

// ---- MFMA projection: Q,K,V = x @ Wq/Wk/Wv, stored bf16 ----
__global__ __launch_bounds__(256) void proj_mfma_kernel(
    const float* __restrict__ x, const unsigned short* __restrict__ wt,
    unsigned short* __restrict__ Q, unsigned short* __restrict__ K,
    unsigned short* __restrict__ V, int n_nodes)
{
    const int w = threadIdx.x >> 6;
    const int l = threadIdx.x & 63;
    const int node0 = blockIdx.x * 64 + w * 16;
    if (node0 >= n_nodes) return;                 // n_nodes % 16 == 0

    const int kc = (l >> 4) * 8;                  // k-chunk within 32
    const int row = node0 + (l & 15);

    // A fragments: 8 k-steps x 8 bf16
    bf16x8 a[8];
    const float* xr = x + (size_t)row * IN_FEAT + kc;
#pragma unroll
    for (int ks = 0; ks < 8; ks++) {
        float4 f0 = *reinterpret_cast<const float4*>(xr + ks * 32);
        float4 f1 = *reinterpret_cast<const float4*>(xr + ks * 32 + 4);
        bf16x8 av;
        av[0] = (short)f2bf(f0.x); av[1] = (short)f2bf(f0.y);
        av[2] = (short)f2bf(f0.z); av[3] = (short)f2bf(f0.w);
        av[4] = (short)f2bf(f1.x); av[5] = (short)f2bf(f1.y);
        av[6] = (short)f2bf(f1.z); av[7] = (short)f2bf(f1.w);
        a[ks] = av;
    }

    const int r0 = node0 + (l >> 4) * 4;
#pragma unroll
    for (int m = 0; m < 3; m++) {
        unsigned short* __restrict__ O = (m == 0) ? Q : (m == 1) ? K : V;
        const unsigned short* wtm = wt + (size_t)m * OUT_TOTAL * IN_FEAT;
#pragma unroll
        for (int nf = 0; nf < 8; nf++) {
            int col = nf * 16 + (l & 15);
            const unsigned short* wcol = wtm + (size_t)col * IN_FEAT + kc;
            f32x4 acc = {0.f, 0.f, 0.f, 0.f};
#pragma unroll
            for (int ks = 0; ks < 8; ks++) {
                bf16x8 b = *reinterpret_cast<const bf16x8*>(wcol + ks * 32);
                acc = __builtin_amdgcn_mfma_f32_16x16x32_bf16(a[ks], b, acc, 0, 0, 0);
            }
#pragma unroll
            for (int j = 0; j < 4; j++)
                O[(size_t)(r0 + j) * OUT_TOTAL + col] = f2bf(acc[j]);
        }
    }
}

// ---- CSR build: degree count ----
__global__ __launch_bounds__(256) void deg_kernel(
    const int* __restrict__ row, int* __restrict__ deg, int n_edges)
{
    int e = blockIdx.x * 256 + threadIdx.x;
    if (e < n_edges) atomicAdd(&deg[row[e]], 1);
}

// ---- CSR build: single-block chunked exclusive scan ----
__global__ __launch_bounds__(1024) void scan_kernel(
    const int* __restrict__ deg, int* __restrict__ off, int n)
{
    const int T = 1024;
    int t = threadIdx.x;
    int chunk = (n + T - 1) / T;
    int b0 = t * chunk;
    int b1 = min(b0 + chunk, n);
    int s = 0;
    for (int i = b0; i < b1; i++) s += deg[i];

    __shared__ int tmp[T];
    tmp[t] = s;
    __syncthreads();
    for (int st = 1; st < T; st <<= 1) {
        int add = (t >= st) ? tmp[t - st] : 0;
        __syncthreads();
        tmp[t] += add;
        __syncthreads();
    }
    int excl = tmp[t] - s;
    for (int i = b0; i < b1; i++) { off[i] = excl; excl += deg[i]; }
    if (t == T - 1) off[n] = tmp[T - 1];
}

// ---- CSR build: scatter col indices into buckets ----
__global__ __launch_bounds__(256) void fill_kernel(
    const int* __restrict__ row, const int* __restrict__ col,
    const int* __restrict__ off, int* __restrict__ cursor,
    int* __restrict__ csr_col, int n_edges)
{
    int e = blockIdx.x * 256 + threadIdx.x;
    if (e < n_edges) {
        int r = row[e];
        int pos = atomicAdd(&cursor[r], 1);
        csr_col[off[r] + pos] = col[e];
    }
}

// ---- fused per-node attention: one wave per node, bf16 Q/K/V ----
__global__ __launch_bounds__(256) void node_attn_kernel(
    const unsigned short* __restrict__ Qb, const unsigned short* __restrict__ Kb,
    const unsigned short* __restrict__ Vb,
    const int* __restrict__ off, const int* __restrict__ csr_col,
    float* __restrict__ out, int n_nodes)
{
    int wave = (blockIdx.x * 256 + threadIdx.x) >> 6;
    if (wave >= n_nodes) return;
    const int node = wave;
    const int lane = threadIdx.x & 63;
    const int h = lane & 3;
    const int slot = lane >> 2;

    const int e0 = off[node];
    const int deg = off[node + 1] - e0;

    bf16x8 qb[4];
    const bf16x8* qp = reinterpret_cast<const bf16x8*>(&Qb[(size_t)node * OUT_TOTAL + h * D_K]);
#pragma unroll
    for (int i = 0; i < 4; i++) qb[i] = qp[i];

    float m = NEG_BIG;
    float ssum = 0.f;
    float acc[D_K];
#pragma unroll
    for (int i = 0; i < D_K; i++) acc[i] = 0.f;

    // prefetched edge index for current chunk
    int cn = -1;
    if (deg > 0) cn = (slot < deg) ? csr_col[e0 + slot] : -1;

    for (int base = 0; base < deg; base += 16) {
        int cn_cur = cn;
        // prefetch next chunk's indices before touching K/V
        int nbase = base + 16;
        if (nbase < deg) {
            int ni = nbase + slot;
            cn = (ni < deg) ? csr_col[e0 + ni] : -1;
        }
        bool act = (cn_cur >= 0);
        int cnc = act ? cn_cur : 0;

        const bf16x8* kp = reinterpret_cast<const bf16x8*>(&Kb[(size_t)cnc * OUT_TOTAL + h * D_K]);
        const bf16x8* vp = reinterpret_cast<const bf16x8*>(&Vb[(size_t)cnc * OUT_TOTAL + h * D_K]);
        bf16x8 kb[4], vb[4];
#pragma unroll
        for (int i = 0; i < 4; i++) kb[i] = kp[i];
#pragma unroll
        for (int i = 0; i < 4; i++) vb[i] = vp[i];

        float d = 0.f;
#pragma unroll
        for (int i = 0; i < 4; i++)
#pragma unroll
            for (int j = 0; j < 8; j++)
                d = fmaf(bf2f((unsigned short)kb[i][j]),
                         bf2f((unsigned short)qb[i][j]), d);

        float s = act ? d * 0.17677669529663689f : NEG_BIG;

        float cmax = s;
        cmax = fmaxf(cmax, __shfl_xor(cmax, 4));
        cmax = fmaxf(cmax, __shfl_xor(cmax, 8));
        cmax = fmaxf(cmax, __shfl_xor(cmax, 16));
        cmax = fmaxf(cmax, __shfl_xor(cmax, 32));
        float m_new = fmaxf(m, cmax);
        float scale = __expf(m - m_new);     // finite sentinel: underflows to 0
        ssum *= scale;
#pragma unroll
        for (int i = 0; i < D_K; i++) acc[i] *= scale;
        m = m_new;

        float wgt = act ? __expf(s - m_new) : 0.f;
        ssum += wgt;

#pragma unroll
        for (int i = 0; i < 4; i++)
#pragma unroll
            for (int j = 0; j < 8; j++)
                acc[i * 8 + j] = fmaf(wgt, bf2f((unsigned short)vb[i][j]), acc[i * 8 + j]);
    }

    ssum += __shfl_xor(ssum, 4);
    ssum += __shfl_xor(ssum, 8);
    ssum += __shfl_xor(ssum, 16);
    ssum += __shfl_xor(ssum, 32);
#pragma unroll
    for (int i = 0; i < D_K; i++) {
        acc[i] += __shfl_xor(acc[i], 4);
        acc[i] += __shfl_xor(acc[i], 8);
        acc[i] += __shfl_xor(acc[i], 16);
        acc[i] += __shfl_xor(acc[i], 32);
    }

    float inv = (ssum > 0.f) ? 1.f / ssum : 0.f;
    float2 w2;
    w2.x = acc[slot * 2 + 0] * inv;
    w2.y = acc[slot * 2 + 1] * inv;
    *reinterpret_cast<float2*>(&out[(size_t)node * OUT_TOTAL + h * D_K + slot * 2]) = w2;
}

extern "C" void kernel_launch(void* const* d_in, const int* in_sizes, int n_in,
                              void* d_out, int out_size, void* d_ws, size_t ws_size,
                              hipStream_t stream)
{
    const float* x  = (const float*)d_in[0];
    const float* Wq = (const float*)d_in[1];
    const float* Wk = (const float*)d_in[2];
    const float* Wv = (const float*)d_in[3];
    const int*   ei = (const int*)d_in[4];
    float* out = (float*)d_out;

    const int n_nodes = in_sizes[0] / IN_FEAT;   // 50000
    const int n_edges = in_sizes[4] / 2;         // 800000
    const int* row = ei;
    const int* col = ei + n_edges;

    char* ws = (char*)d_ws;
    unsigned short* Q = (unsigned short*)ws;  ws += (size_t)n_nodes * OUT_TOTAL * sizeof(unsigned short);
    unsigned short* K = (unsigned short*)ws;  ws += (size_t)n_nodes * OUT_TOTAL * sizeof(unsigned short);
    unsigned short* V = (unsigned short*)ws;  ws += (size_t)n_nodes * OUT_TOTAL * sizeof(unsigned short);
    unsigned short* wt = (unsigned short*)ws; ws += (size_t)3 * OUT_TOTAL * IN_FEAT * sizeof(unsigned short);
    int* deg = (int*)ws;                      ws += (size_t)n_nodes * sizeof(int);
    int* off = (int*)ws;                      ws += (size_t)(n_nodes + 1) * sizeof(int);
    int* cursor = (int*)ws;                   ws += (size_t)n_nodes * sizeof(int);
    int* csr_col = (int*)ws;                  ws += (size_t)n_edges * sizeof(int);

    (void)hipMemsetAsync(deg, 0, (size_t)n_nodes * sizeof(int), stream);
    (void)hipMemsetAsync(cursor, 0, (size_t)n_nodes * sizeof(int), stream);

    pack_w_kernel<<<(3 * OUT_TOTAL * IN_FEAT + 255) / 256, 256, 0, stream>>>(Wq, Wk, Wv, wt);
    proj_mfma_kernel<<<(n_nodes + 63) / 64, 256, 0, stream>>>(x, wt, Q, K, V, n_nodes);

    int eb = (n_edges + 255) / 256;
    deg_kernel<<<eb, 256, 0, stream>>>(row, deg, n_edges);
    scan_kernel<<<1, 1024, 0, stream>>>(deg, off, n_nodes);
    fill_kernel<<<eb, 256, 0, stream>>>(row, col, off, cursor, csr_col, n_edges);

    node_attn_kernel<<<(n_nodes + 3) / 4, 256, 0, stream>>>(Q, K, V, off, csr_col, out, n_nodes);
}

// Round 6
// 291.489 us; speedup vs baseline: 20.1045x; 1.1994x over previous
//
#include <hip/hip_runtime.h>
#include <hip/hip_bf16.h>

#define HEADS 4
#define D_K 32
#define IN_FEAT 256
#define OUT_TOTAL (HEADS * D_K)   // 128
#define NEG_BIG -3.0e38f
#define PROJ_ROWS 128             // rows per projection block

typedef __attribute__((ext_vector_type(8))) short bf16x8;
typedef __attribute__((ext_vector_type(4))) float f32x4;

// f32 -> bf16 round-to-nearest-even (finite inputs)
__device__ __forceinline__ unsigned short f2bf(float f) {
    unsigned u = __float_as_uint(f);
    u += 0x7fffu + ((u >> 16) & 1u);
    return (unsigned short)(u >> 16);
}
__device__ __forceinline__ float bf2f(unsigned short u) {
    return __uint_as_float(((unsigned)u) << 16);
}

// ---- pack W transposed + LDS-swizzled bf16 ----
// wt[m][col][k ^ ((col&7)<<3)] = bf16(W_m[k][col])
// The XOR pre-applies the LDS bank-conflict swizzle so the kernel can do a
// LINEAR global->LDS copy and a swizzled ds_read (both-sides rule, T2/G21).
__global__ __launch_bounds__(256) void pack_w_kernel(
    const float* __restrict__ Wq, const float* __restrict__ Wk,
    const float* __restrict__ Wv, unsigned short* __restrict__ wt)
{
    int idx = blockIdx.x * 256 + threadIdx.x;     // over 3*128*256
    if (idx >= 3 * OUT_TOTAL * IN_FEAT) return;
    int k = idx & 255;
    int c = (idx >> 8) & 127;
    int m = idx >> 15;
    const float* W = (m == 0) ? Wq : (m == 1) ? Wk : Wv;
    int ksw = k ^ ((c & 7) << 3);
    wt[(m << 15) | (c << 8) | ksw] = f2bf(W[k * OUT_TOTAL + c]);
}

// ---- MFMA projection: one matrix per block-slice, W staged in LDS ----
// grid = 3 * bpm; block = 256 thr / 4 waves; block tile = 128 rows x 128 cols.
// Wave: 2 row-frags x 8 col-frags x 8 k-steps = 128 MFMA; each B ds_read
// feeds 2 MFMAs. LDS image is the pre-swizzled wt slice (linear copy).
__global__ __launch_bounds__(256, 2) void proj_mfma_kernel(
    const float* __restrict__ x, const unsigned short* __restrict__ wt,
    unsigned short* __restrict__ Q, unsigned short* __restrict__ K,
    unsigned short* __restrict__ V, int n_nodes, int bpm)
{
    __shared__ unsigned short wlds[OUT_TOTAL * IN_FEAT];   // 64 KB

    const int m  = blockIdx.x / bpm;
    const int rb = blockIdx.x % bpm;
    const int t  = threadIdx.x;
    const int w  = t >> 6, l = t & 63;

    // stage W-mat (64 KB) into LDS: linear float4 copy, coalesced
    {
        const float4* src = reinterpret_cast<const float4*>(wt + (size_t)m * OUT_TOTAL * IN_FEAT);
        float4* dst = reinterpret_cast<float4*>(wlds);
#pragma unroll
        for (int i = 0; i < 16; i++)
            dst[i * 256 + t] = src[i * 256 + t];
    }
    __syncthreads();

    const int node0 = rb * PROJ_ROWS + w * 32;    // wave owns 32 rows
    const int kc = (l >> 4) * 8;                  // k-chunk within 32
    const int cb = l & 15;

    // A fragments: 2 row-frags x 8 k-steps, f32 -> bf16 in-register
    bf16x8 a[2][8];
#pragma unroll
    for (int rf = 0; rf < 2; rf++) {
        int row = node0 + rf * 16 + (l & 15);
        row = min(row, n_nodes - 1);              // clamp; stores are guarded
        const float* xr = x + (size_t)row * IN_FEAT + kc;
#pragma unroll
        for (int ks = 0; ks < 8; ks++) {
            float4 f0 = *reinterpret_cast<const float4*>(xr + ks * 32);
            float4 f1 = *reinterpret_cast<const float4*>(xr + ks * 32 + 4);
            bf16x8 av;
            av[0] = (short)f2bf(f0.x); av[1] = (short)f2bf(f0.y);
            av[2] = (short)f2bf(f0.z); av[3] = (short)f2bf(f0.w);
            av[4] = (short)f2bf(f1.x); av[5] = (short)f2bf(f1.y);
            av[6] = (short)f2bf(f1.z); av[7] = (short)f2bf(f1.w);
            a[rf][ks] = av;
        }
    }

    f32x4 acc[2][8];
#pragma unroll
    for (int rf = 0; rf < 2; rf++)
#pragma unroll
        for (int nf = 0; nf < 8; nf++) acc[rf][nf] = (f32x4){0.f, 0.f, 0.f, 0.f};

#pragma unroll
    for (int nf = 0; nf < 8; nf++) {
        const int col = nf * 16 + cb;
        const int swz = (col & 7) << 3;
        const unsigned short* wp = &wlds[col * IN_FEAT];
#pragma unroll
        for (int ks = 0; ks < 8; ks++) {
            bf16x8 b = *reinterpret_cast<const bf16x8*>(wp + ((kc + ks * 32) ^ swz));
            acc[0][nf] = __builtin_amdgcn_mfma_f32_16x16x32_bf16(a[0][ks], b, acc[0][nf], 0, 0, 0);
            acc[1][nf] = __builtin_amdgcn_mfma_f32_16x16x32_bf16(a[1][ks], b, acc[1][nf], 0, 0, 0);
        }
    }

    unsigned short* __restrict__ O = (m == 0) ? Q : (m == 1) ? K : V;
#pragma unroll
    for (int rf = 0; rf < 2; rf++) {
        int r0 = node0 + rf * 16 + (l >> 4) * 4;
#pragma unroll
        for (int nf = 0; nf < 8; nf++) {
            int col = nf * 16 + cb;
#pragma unroll
            for (int j = 0; j < 4; j++)
                if (r0 + j < n_nodes)
                    O[(size_t)(r0 + j) * OUT_TOTAL + col] = f2bf(acc[rf][nf][j]);
        }
    }
}

// ---- CSR build: degree count ----
__global__ __launch_bounds__(256) void deg_kernel(
    const int* __restrict__ row, int* __restrict__ deg, int n_edges)
{
    int e = blockIdx.x * 256 + threadIdx.x;
    if (e < n_edges) atomicAdd(&deg[row[e]], 1);
}

// ---- CSR build: single-block chunked exclusive scan ----
__global__ __launch_bounds__(1024) void scan_kernel(
    const int* __restrict__ deg, int* __restrict__ off, int n)
{
    const int T = 1024;
    int t = threadIdx.x;
    int chunk = (n + T - 1) / T;
    int b0 = t * chunk;
    int b1 = min(b0 + chunk, n);
    int s = 0;
    for (int i = b0; i < b1; i++) s += deg[i];

    __shared__ int tmp[T];
    tmp[t] = s;
    __syncthreads();
    for (int st = 1; st < T; st <<= 1) {
        int add = (t >= st) ? tmp[t - st] : 0;
        __syncthreads();
        tmp[t] += add;
        __syncthreads();
    }
    int excl = tmp[t] - s;
    for (int i = b0; i < b1; i++) { off[i] = excl; excl += deg[i]; }
    if (t == T - 1) off[n] = tmp[T - 1];
}

// ---- CSR build: scatter col indices into buckets ----
__global__ __launch_bounds__(256) void fill_kernel(
    const int* __restrict__ row, const int* __restrict__ col,
    const int* __restrict__ off, int* __restrict__ cursor,
    int* __restrict__ csr_col, int n_edges)
{
    int e = blockIdx.x * 256 + threadIdx.x;
    if (e < n_edges) {
        int r = row[e];
        int pos = atomicAdd(&cursor[r], 1);
        csr_col[off[r] + pos] = col[e];
    }
}

// ---- fused per-node attention: one wave per node, bf16 Q/K/V ----
__global__ __launch_bounds__(256) void node_attn_kernel(
    const unsigned short* __restrict__ Qb, const unsigned short* __restrict__ Kb,
    const unsigned short* __restrict__ Vb,
    const int* __restrict__ off, const int* __restrict__ csr_col,
    float* __restrict__ out, int n_nodes)
{
    int wave = (blockIdx.x * 256 + threadIdx.x) >> 6;
    if (wave >= n_nodes) return;
    const int node = wave;
    const int lane = threadIdx.x & 63;
    const int h = lane & 3;
    const int slot = lane >> 2;

    const int e0 = off[node];
    const int deg = off[node + 1] - e0;

    bf16x8 qb[4];
    const bf16x8* qp = reinterpret_cast<const bf16x8*>(&Qb[(size_t)node * OUT_TOTAL + h * D_K]);
#pragma unroll
    for (int i = 0; i < 4; i++) qb[i] = qp[i];

    float m = NEG_BIG;
    float ssum = 0.f;
    float acc[D_K];
#pragma unroll
    for (int i = 0; i < D_K; i++) acc[i] = 0.f;

    int cn = -1;
    if (deg > 0) cn = (slot < deg) ? csr_col[e0 + slot] : -1;

    for (int base = 0; base < deg; base += 16) {
        int cn_cur = cn;
        int nbase = base + 16;
        if (nbase < deg) {
            int ni = nbase + slot;
            cn = (ni < deg) ? csr_col[e0 + ni] : -1;
        }
        bool act = (cn_cur >= 0);
        int cnc = act ? cn_cur : 0;

        const bf16x8* kp = reinterpret_cast<const bf16x8*>(&Kb[(size_t)cnc * OUT_TOTAL + h * D_K]);
        const bf16x8* vp = reinterpret_cast<const bf16x8*>(&Vb[(size_t)cnc * OUT_TOTAL + h * D_K]);
        bf16x8 kb[4], vb[4];
#pragma unroll
        for (int i = 0; i < 4; i++) kb[i] = kp[i];
#pragma unroll
        for (int i = 0; i < 4; i++) vb[i] = vp[i];

        float d = 0.f;
#pragma unroll
        for (int i = 0; i < 4; i++)
#pragma unroll
            for (int j = 0; j < 8; j++)
                d = fmaf(bf2f((unsigned short)kb[i][j]),
                         bf2f((unsigned short)qb[i][j]), d);

        float s = act ? d * 0.17677669529663689f : NEG_BIG;

        float cmax = s;
        cmax = fmaxf(cmax, __shfl_xor(cmax, 4));
        cmax = fmaxf(cmax, __shfl_xor(cmax, 8));
        cmax = fmaxf(cmax, __shfl_xor(cmax, 16));
        cmax = fmaxf(cmax, __shfl_xor(cmax, 32));
        float m_new = fmaxf(m, cmax);
        float scale = __expf(m - m_new);
        ssum *= scale;
#pragma unroll
        for (int i = 0; i < D_K; i++) acc[i] *= scale;
        m = m_new;

        float wgt = act ? __expf(s - m_new) : 0.f;
        ssum += wgt;

#pragma unroll
        for (int i = 0; i < 4; i++)
#pragma unroll
            for (int j = 0; j < 8; j++)
                acc[i * 8 + j] = fmaf(wgt, bf2f((unsigned short)vb[i][j]), acc[i * 8 + j]);
    }

    ssum += __shfl_xor(ssum, 4);
    ssum += __shfl_xor(ssum, 8);
    ssum += __shfl_xor(ssum, 16);
    ssum += __shfl_xor(ssum, 32);
#pragma unroll
    for (int i = 0; i < D_K; i++) {
        acc[i] += __shfl_xor(acc[i], 4);
        acc[i] += __shfl_xor(acc[i], 8);
        acc[i] += __shfl_xor(acc[i], 16);
        acc[i] += __shfl_xor(acc[i], 32);
    }

    float inv = (ssum > 0.f) ? 1.f / ssum : 0.f;
    float2 w2;
    w2.x = acc[slot * 2 + 0] * inv;
    w2.y = acc[slot * 2 + 1] * inv;
    *reinterpret_cast<float2*>(&out[(size_t)node * OUT_TOTAL + h * D_K + slot * 2]) = w2;
}

extern "C" void kernel_launch(void* const* d_in, const int* in_sizes, int n_in,
                              void* d_out, int out_size, void* d_ws, size_t ws_size,
                              hipStream_t stream)
{
    const float* x  = (const float*)d_in[0];
    const float* Wq = (const float*)d_in[1];
    const float* Wk = (const float*)d_in[2];
    const float* Wv = (const float*)d_in[3];
    const int*   ei = (const int*)d_in[4];
    float* out = (float*)d_out;

    const int n_nodes = in_sizes[0] / IN_FEAT;   // 50000
    const int n_edges = in_sizes[4] / 2;         // 800000
    const int* row = ei;
    const int* col = ei + n_edges;

    char* ws = (char*)d_ws;
    unsigned short* Q = (unsigned short*)ws;  ws += (size_t)n_nodes * OUT_TOTAL * sizeof(unsigned short);
    unsigned short* K = (unsigned short*)ws;  ws += (size_t)n_nodes * OUT_TOTAL * sizeof(unsigned short);
    unsigned short* V = (unsigned short*)ws;  ws += (size_t)n_nodes * OUT_TOTAL * sizeof(unsigned short);
    unsigned short* wt = (unsigned short*)ws; ws += (size_t)3 * OUT_TOTAL * IN_FEAT * sizeof(unsigned short);
    int* deg = (int*)ws;                      ws += (size_t)n_nodes * sizeof(int);
    int* off = (int*)ws;                      ws += (size_t)(n_nodes + 1) * sizeof(int);
    int* cursor = (int*)ws;                   ws += (size_t)n_nodes * sizeof(int);
    int* csr_col = (int*)ws;                  ws += (size_t)n_edges * sizeof(int);

    (void)hipMemsetAsync(deg, 0, (size_t)n_nodes * sizeof(int), stream);
    (void)hipMemsetAsync(cursor, 0, (size_t)n_nodes * sizeof(int), stream);

    pack_w_kernel<<<(3 * OUT_TOTAL * IN_FEAT + 255) / 256, 256, 0, stream>>>(Wq, Wk, Wv, wt);

    int bpm = (n_nodes + PROJ_ROWS - 1) / PROJ_ROWS;
    proj_mfma_kernel<<<3 * bpm, 256, 0, stream>>>(x, wt, Q, K, V, n_nodes, bpm);

    int eb = (n_edges + 255) / 256;
    deg_kernel<<<eb, 256, 0, stream>>>(row, deg, n_edges);
    scan_kernel<<<1, 1024, 0, stream>>>(deg, off, n_nodes);
    fill_kernel<<<eb, 256, 0, stream>>>(row, col, off, cursor, csr_col, n_edges);

    node_attn_kernel<<<(n_nodes + 3) / 4, 256, 0, stream>>>(Q, K, V, off, csr_col, out, n_nodes);
}

// Round 7
// 273.431 us; speedup vs baseline: 21.4323x; 1.0660x over previous
//
#include <hip/hip_runtime.h>
#include <hip/hip_bf16.h>

#define HEADS 4
#define D_K 32
#define IN_FEAT 256
#define OUT_TOTAL (HEADS * D_K)   // 128
#define NEG_BIG -3.0e38f
#define PROJ_ROWS 128             // rows per projection block

typedef __attribute__((ext_vector_type(8))) short bf16x8;
typedef __attribute__((ext_vector_type(4))) float f32x4;

// f32 -> bf16 round-to-nearest-even (finite inputs)
__device__ __forceinline__ unsigned short f2bf(float f) {
    unsigned u = __float_as_uint(f);
    u += 0x7fffu + ((u >> 16) & 1u);
    return (unsigned short)(u >> 16);
}
__device__ __forceinline__ float bf2f(unsigned short u) {
    return __uint_as_float(((unsigned)u) << 16);
}

// ---- pack W transposed + LDS-swizzled bf16 ----
// wt[m][col][k ^ ((col&7)<<3)] = bf16(W_m[k][col])
__global__ __launch_bounds__(256) void pack_w_kernel(
    const float* __restrict__ Wq, const float* __restrict__ Wk,
    const float* __restrict__ Wv, unsigned short* __restrict__ wt)
{
    int idx = blockIdx.x * 256 + threadIdx.x;     // over 3*128*256
    if (idx >= 3 * OUT_TOTAL * IN_FEAT) return;
    int k = idx & 255;
    int c = (idx >> 8) & 127;
    int m = idx >> 15;
    const float* W = (m == 0) ? Wq : (m == 1) ? Wk : Wv;
    int ksw = k ^ ((c & 7) << 3);
    wt[(m << 15) | (c << 8) | ksw] = f2bf(W[k * OUT_TOTAL + c]);
}

// ---- MFMA projection: one matrix per block-slice, W staged in LDS ----
__global__ __launch_bounds__(256, 2) void proj_mfma_kernel(
    const float* __restrict__ x, const unsigned short* __restrict__ wt,
    unsigned short* __restrict__ Q, unsigned short* __restrict__ K,
    unsigned short* __restrict__ V, int n_nodes, int bpm)
{
    __shared__ unsigned short wlds[OUT_TOTAL * IN_FEAT];   // 64 KB

    const int m  = blockIdx.x / bpm;
    const int rb = blockIdx.x % bpm;
    const int t  = threadIdx.x;
    const int w  = t >> 6, l = t & 63;

    // stage W-mat (64 KB) into LDS: linear float4 copy, coalesced
    {
        const float4* src = reinterpret_cast<const float4*>(wt + (size_t)m * OUT_TOTAL * IN_FEAT);
        float4* dst = reinterpret_cast<float4*>(wlds);
#pragma unroll
        for (int i = 0; i < 16; i++)
            dst[i * 256 + t] = src[i * 256 + t];
    }
    __syncthreads();

    const int node0 = rb * PROJ_ROWS + w * 32;    // wave owns 32 rows
    const int kc = (l >> 4) * 8;                  // k-chunk within 32
    const int cb = l & 15;

    // A fragments: 2 row-frags x 8 k-steps, f32 -> bf16 in-register
    bf16x8 a[2][8];
#pragma unroll
    for (int rf = 0; rf < 2; rf++) {
        int row = node0 + rf * 16 + (l & 15);
        row = min(row, n_nodes - 1);              // clamp; stores are guarded
        const float* xr = x + (size_t)row * IN_FEAT + kc;
#pragma unroll
        for (int ks = 0; ks < 8; ks++) {
            float4 f0 = *reinterpret_cast<const float4*>(xr + ks * 32);
            float4 f1 = *reinterpret_cast<const float4*>(xr + ks * 32 + 4);
            bf16x8 av;
            av[0] = (short)f2bf(f0.x); av[1] = (short)f2bf(f0.y);
            av[2] = (short)f2bf(f0.z); av[3] = (short)f2bf(f0.w);
            av[4] = (short)f2bf(f1.x); av[5] = (short)f2bf(f1.y);
            av[6] = (short)f2bf(f1.z); av[7] = (short)f2bf(f1.w);
            a[rf][ks] = av;
        }
    }

    f32x4 acc[2][8];
#pragma unroll
    for (int rf = 0; rf < 2; rf++)
#pragma unroll
        for (int nf = 0; nf < 8; nf++) acc[rf][nf] = (f32x4){0.f, 0.f, 0.f, 0.f};

#pragma unroll
    for (int nf = 0; nf < 8; nf++) {
        const int col = nf * 16 + cb;
        const int swz = (col & 7) << 3;
        const unsigned short* wp = &wlds[col * IN_FEAT];
#pragma unroll
        for (int ks = 0; ks < 8; ks++) {
            bf16x8 b = *reinterpret_cast<const bf16x8*>(wp + ((kc + ks * 32) ^ swz));
            acc[0][nf] = __builtin_amdgcn_mfma_f32_16x16x32_bf16(a[0][ks], b, acc[0][nf], 0, 0, 0);
            acc[1][nf] = __builtin_amdgcn_mfma_f32_16x16x32_bf16(a[1][ks], b, acc[1][nf], 0, 0, 0);
        }
    }

    unsigned short* __restrict__ O = (m == 0) ? Q : (m == 1) ? K : V;
#pragma unroll
    for (int rf = 0; rf < 2; rf++) {
        int r0 = node0 + rf * 16 + (l >> 4) * 4;
#pragma unroll
        for (int nf = 0; nf < 8; nf++) {
            int col = nf * 16 + cb;
#pragma unroll
            for (int j = 0; j < 4; j++)
                if (r0 + j < n_nodes)
                    O[(size_t)(r0 + j) * OUT_TOTAL + col] = f2bf(acc[rf][nf][j]);
        }
    }
}

// ---- CSR build: degree count ----
__global__ __launch_bounds__(256) void deg_kernel(
    const int* __restrict__ row, int* __restrict__ deg, int n_edges)
{
    int e = blockIdx.x * 256 + threadIdx.x;
    if (e < n_edges) atomicAdd(&deg[row[e]], 1);
}

// ---- CSR build: single-block chunked exclusive scan ----
__global__ __launch_bounds__(1024) void scan_kernel(
    const int* __restrict__ deg, int* __restrict__ off, int n)
{
    const int T = 1024;
    int t = threadIdx.x;
    int chunk = (n + T - 1) / T;
    int b0 = t * chunk;
    int b1 = min(b0 + chunk, n);
    int s = 0;
    for (int i = b0; i < b1; i++) s += deg[i];

    __shared__ int tmp[T];
    tmp[t] = s;
    __syncthreads();
    for (int st = 1; st < T; st <<= 1) {
        int add = (t >= st) ? tmp[t - st] : 0;
        __syncthreads();
        tmp[t] += add;
        __syncthreads();
    }
    int excl = tmp[t] - s;
    for (int i = b0; i < b1; i++) { off[i] = excl; excl += deg[i]; }
    if (t == T - 1) off[n] = tmp[T - 1];
}

// ---- CSR build: scatter col indices into buckets ----
__global__ __launch_bounds__(256) void fill_kernel(
    const int* __restrict__ row, const int* __restrict__ col,
    const int* __restrict__ off, int* __restrict__ cursor,
    int* __restrict__ csr_col, int n_edges)
{
    int e = blockIdx.x * 256 + threadIdx.x;
    if (e < n_edges) {
        int r = row[e];
        int pos = atomicAdd(&cursor[r], 1);
        csr_col[off[r] + pos] = col[e];
    }
}

// ---- fused per-node attention: one wave per node, bf16 Q/K/V ----
// lane = slot*4 + h. Epilogue: reduce-scatter (recursive halving) instead of
// all-reduce: 30 shuffles vs 128.
__global__ __launch_bounds__(256) void node_attn_kernel(
    const unsigned short* __restrict__ Qb, const unsigned short* __restrict__ Kb,
    const unsigned short* __restrict__ Vb,
    const int* __restrict__ off, const int* __restrict__ csr_col,
    float* __restrict__ out, int n_nodes)
{
    int wave = (blockIdx.x * 256 + threadIdx.x) >> 6;
    if (wave >= n_nodes) return;
    const int node = wave;
    const int lane = threadIdx.x & 63;
    const int h = lane & 3;
    const int slot = lane >> 2;

    const int e0 = off[node];
    const int deg = off[node + 1] - e0;

    bf16x8 qb[4];
    const bf16x8* qp = reinterpret_cast<const bf16x8*>(&Qb[(size_t)node * OUT_TOTAL + h * D_K]);
#pragma unroll
    for (int i = 0; i < 4; i++) qb[i] = qp[i];

    float m = NEG_BIG;
    float ssum = 0.f;
    float acc[D_K];
#pragma unroll
    for (int i = 0; i < D_K; i++) acc[i] = 0.f;

    int cn = -1;
    if (deg > 0) cn = (slot < deg) ? csr_col[e0 + slot] : -1;

    for (int base = 0; base < deg; base += 16) {
        int cn_cur = cn;
        int nbase = base + 16;
        if (nbase < deg) {
            int ni = nbase + slot;
            cn = (ni < deg) ? csr_col[e0 + ni] : -1;
        }
        bool act = (cn_cur >= 0);
        int cnc = act ? cn_cur : 0;

        const bf16x8* kp = reinterpret_cast<const bf16x8*>(&Kb[(size_t)cnc * OUT_TOTAL + h * D_K]);
        const bf16x8* vp = reinterpret_cast<const bf16x8*>(&Vb[(size_t)cnc * OUT_TOTAL + h * D_K]);
        bf16x8 kb[4], vb[4];
#pragma unroll
        for (int i = 0; i < 4; i++) kb[i] = kp[i];
#pragma unroll
        for (int i = 0; i < 4; i++) vb[i] = vp[i];

        float d = 0.f;
#pragma unroll
        for (int i = 0; i < 4; i++)
#pragma unroll
            for (int j = 0; j < 8; j++)
                d = fmaf(bf2f((unsigned short)kb[i][j]),
                         bf2f((unsigned short)qb[i][j]), d);

        float s = act ? d * 0.17677669529663689f : NEG_BIG;

        float cmax = s;
        cmax = fmaxf(cmax, __shfl_xor(cmax, 4));
        cmax = fmaxf(cmax, __shfl_xor(cmax, 8));
        cmax = fmaxf(cmax, __shfl_xor(cmax, 16));
        cmax = fmaxf(cmax, __shfl_xor(cmax, 32));

        // exact skip-rescale: only pay the O-wide pass when the max grew
        if (__any(cmax > m)) {
            float m_new = fmaxf(m, cmax);
            float scale = __expf(m - m_new);   // ==1 where this group's max unchanged
            ssum *= scale;
#pragma unroll
            for (int i = 0; i < D_K; i++) acc[i] *= scale;
            m = m_new;
        }

        float wgt = act ? __expf(s - m) : 0.f;
        ssum += wgt;

#pragma unroll
        for (int i = 0; i < 4; i++)
#pragma unroll
            for (int j = 0; j < 8; j++)
                acc[i * 8 + j] = fmaf(wgt, bf2f((unsigned short)vb[i][j]), acc[i * 8 + j]);
    }

    // ssum: full butterfly (all lanes need it)
    ssum += __shfl_xor(ssum, 4);
    ssum += __shfl_xor(ssum, 8);
    ssum += __shfl_xor(ssum, 16);
    ssum += __shfl_xor(ssum, 32);

    // acc: reduce-scatter over the 16-lane head group (masks 32,16,8,4).
    // This lane finishes holding dims [2*slot, 2*slot+2) of head h.
    float r16[16];
    {
        const int b = (lane >> 5) & 1;          // slot bit 3
#pragma unroll
        for (int j = 0; j < 16; j++) {
            float send = b ? acc[j] : acc[j + 16];
            float keep = b ? acc[j + 16] : acc[j];
            r16[j] = keep + __shfl_xor(send, 32);
        }
    }
    float r8[8];
    {
        const int b = (lane >> 4) & 1;          // slot bit 2
#pragma unroll
        for (int j = 0; j < 8; j++) {
            float send = b ? r16[j] : r16[j + 8];
            float keep = b ? r16[j + 8] : r16[j];
            r8[j] = keep + __shfl_xor(send, 16);
        }
    }
    float r4[4];
    {
        const int b = (lane >> 3) & 1;          // slot bit 1
#pragma unroll
        for (int j = 0; j < 4; j++) {
            float send = b ? r8[j] : r8[j + 4];
            float keep = b ? r8[j + 4] : r8[j];
            r4[j] = keep + __shfl_xor(send, 8);
        }
    }
    float r2[2];
    {
        const int b = (lane >> 2) & 1;          // slot bit 0
#pragma unroll
        for (int j = 0; j < 2; j++) {
            float send = b ? r4[j] : r4[j + 2];
            float keep = b ? r4[j + 2] : r4[j];
            r2[j] = keep + __shfl_xor(send, 4);
        }
    }

    float inv = (ssum > 0.f) ? 1.f / ssum : 0.f;
    float2 w2;
    w2.x = r2[0] * inv;
    w2.y = r2[1] * inv;
    *reinterpret_cast<float2*>(&out[(size_t)node * OUT_TOTAL + h * D_K + slot * 2]) = w2;
}

extern "C" void kernel_launch(void* const* d_in, const int* in_sizes, int n_in,
                              void* d_out, int out_size, void* d_ws, size_t ws_size,
                              hipStream_t stream)
{
    const float* x  = (const float*)d_in[0];
    const float* Wq = (const float*)d_in[1];
    const float* Wk = (const float*)d_in[2];
    const float* Wv = (const float*)d_in[3];
    const int*   ei = (const int*)d_in[4];
    float* out = (float*)d_out;

    const int n_nodes = in_sizes[0] / IN_FEAT;   // 50000
    const int n_edges = in_sizes[4] / 2;         // 800000
    const int* row = ei;
    const int* col = ei + n_edges;

    char* ws = (char*)d_ws;
    unsigned short* Q = (unsigned short*)ws;  ws += (size_t)n_nodes * OUT_TOTAL * sizeof(unsigned short);
    unsigned short* K = (unsigned short*)ws;  ws += (size_t)n_nodes * OUT_TOTAL * sizeof(unsigned short);
    unsigned short* V = (unsigned short*)ws;  ws += (size_t)n_nodes * OUT_TOTAL * sizeof(unsigned short);
    unsigned short* wt = (unsigned short*)ws; ws += (size_t)3 * OUT_TOTAL * IN_FEAT * sizeof(unsigned short);
    int* deg = (int*)ws;                      ws += (size_t)n_nodes * sizeof(int);
    int* off = (int*)ws;                      ws += (size_t)(n_nodes + 1) * sizeof(int);
    int* cursor = (int*)ws;                   ws += (size_t)n_nodes * sizeof(int);
    int* csr_col = (int*)ws;                  ws += (size_t)n_edges * sizeof(int);

    (void)hipMemsetAsync(deg, 0, (size_t)n_nodes * sizeof(int), stream);
    (void)hipMemsetAsync(cursor, 0, (size_t)n_nodes * sizeof(int), stream);

    pack_w_kernel<<<(3 * OUT_TOTAL * IN_FEAT + 255) / 256, 256, 0, stream>>>(Wq, Wk, Wv, wt);

    int bpm = (n_nodes + PROJ_ROWS - 1) / PROJ_ROWS;
    proj_mfma_kernel<<<3 * bpm, 256, 0, stream>>>(x, wt, Q, K, V, n_nodes, bpm);

    int eb = (n_edges + 255) / 256;
    deg_kernel<<<eb, 256, 0, stream>>>(row, deg, n_edges);
    scan_kernel<<<1, 1024, 0, stream>>>(deg, off, n_nodes);
    fill_kernel<<<eb, 256, 0, stream>>>(row, col, off, cursor, csr_col, n_edges);

    node_attn_kernel<<<(n_nodes + 3) / 4, 256, 0, stream>>>(Q, K, V, off, csr_col, out, n_nodes);
}

// Round 8
// 204.386 us; speedup vs baseline: 28.6724x; 1.3378x over previous
//
#include <hip/hip_runtime.h>
#include <hip/hip_bf16.h>

#define HEADS 4
#define D_K 32
#define IN_FEAT 256
#define OUT_TOTAL (HEADS * D_K)   // 128
#define NEG_BIG -3.0e38f
#define PROJ_ROWS 128             // rows per projection block
#define SCAN_T 1024

typedef __attribute__((ext_vector_type(8))) short bf16x8;
typedef __attribute__((ext_vector_type(4))) float f32x4;

// f32 -> bf16 round-to-nearest-even (finite inputs)
__device__ __forceinline__ unsigned short f2bf(float f) {
    unsigned u = __float_as_uint(f);
    u += 0x7fffu + ((u >> 16) & 1u);
    return (unsigned short)(u >> 16);
}
__device__ __forceinline__ float bf2f(unsigned short u) {
    return __uint_as_float(((unsigned)u) << 16);
}

// ---- pack W transposed + LDS-swizzled bf16 ----
// wt[m][col][k ^ ((col&7)<<3)] = bf16(W_m[k][col])
__global__ __launch_bounds__(256) void pack_w_kernel(
    const float* __restrict__ Wq, const float* __restrict__ Wk,
    const float* __restrict__ Wv, unsigned short* __restrict__ wt)
{
    int idx = blockIdx.x * 256 + threadIdx.x;     // over 3*128*256
    if (idx >= 3 * OUT_TOTAL * IN_FEAT) return;
    int k = idx & 255;
    int c = (idx >> 8) & 127;
    int m = idx >> 15;
    const float* W = (m == 0) ? Wq : (m == 1) ? Wk : Wv;
    int ksw = k ^ ((c & 7) << 3);
    wt[(m << 15) | (c << 8) | ksw] = f2bf(W[k * OUT_TOTAL + c]);
}

// ---- MFMA projection: one matrix per block-slice, W staged in LDS ----
__global__ __launch_bounds__(256, 2) void proj_mfma_kernel(
    const float* __restrict__ x, const unsigned short* __restrict__ wt,
    unsigned short* __restrict__ Q, unsigned short* __restrict__ K,
    unsigned short* __restrict__ V, int n_nodes, int bpm)
{
    __shared__ unsigned short wlds[OUT_TOTAL * IN_FEAT];   // 64 KB

    const int m  = blockIdx.x / bpm;
    const int rb = blockIdx.x % bpm;
    const int t  = threadIdx.x;
    const int w  = t >> 6, l = t & 63;

    // stage W-mat (64 KB) into LDS: linear float4 copy, coalesced
    {
        const float4* src = reinterpret_cast<const float4*>(wt + (size_t)m * OUT_TOTAL * IN_FEAT);
        float4* dst = reinterpret_cast<float4*>(wlds);
#pragma unroll
        for (int i = 0; i < 16; i++)
            dst[i * 256 + t] = src[i * 256 + t];
    }
    __syncthreads();

    const int node0 = rb * PROJ_ROWS + w * 32;    // wave owns 32 rows
    const int kc = (l >> 4) * 8;                  // k-chunk within 32
    const int cb = l & 15;

    // A fragments: 2 row-frags x 8 k-steps, f32 -> bf16 in-register
    bf16x8 a[2][8];
#pragma unroll
    for (int rf = 0; rf < 2; rf++) {
        int row = node0 + rf * 16 + (l & 15);
        row = min(row, n_nodes - 1);              // clamp; stores are guarded
        const float* xr = x + (size_t)row * IN_FEAT + kc;
#pragma unroll
        for (int ks = 0; ks < 8; ks++) {
            float4 f0 = *reinterpret_cast<const float4*>(xr + ks * 32);
            float4 f1 = *reinterpret_cast<const float4*>(xr + ks * 32 + 4);
            bf16x8 av;
            av[0] = (short)f2bf(f0.x); av[1] = (short)f2bf(f0.y);
            av[2] = (short)f2bf(f0.z); av[3] = (short)f2bf(f0.w);
            av[4] = (short)f2bf(f1.x); av[5] = (short)f2bf(f1.y);
            av[6] = (short)f2bf(f1.z); av[7] = (short)f2bf(f1.w);
            a[rf][ks] = av;
        }
    }

    f32x4 acc[2][8];
#pragma unroll
    for (int rf = 0; rf < 2; rf++)
#pragma unroll
        for (int nf = 0; nf < 8; nf++) acc[rf][nf] = (f32x4){0.f, 0.f, 0.f, 0.f};

#pragma unroll
    for (int nf = 0; nf < 8; nf++) {
        const int col = nf * 16 + cb;
        const int swz = (col & 7) << 3;
        const unsigned short* wp = &wlds[col * IN_FEAT];
#pragma unroll
        for (int ks = 0; ks < 8; ks++) {
            bf16x8 b = *reinterpret_cast<const bf16x8*>(wp + ((kc + ks * 32) ^ swz));
            acc[0][nf] = __builtin_amdgcn_mfma_f32_16x16x32_bf16(a[0][ks], b, acc[0][nf], 0, 0, 0);
            acc[1][nf] = __builtin_amdgcn_mfma_f32_16x16x32_bf16(a[1][ks], b, acc[1][nf], 0, 0, 0);
        }
    }

    unsigned short* __restrict__ O = (m == 0) ? Q : (m == 1) ? K : V;
#pragma unroll
    for (int rf = 0; rf < 2; rf++) {
        int r0 = node0 + rf * 16 + (l >> 4) * 4;
#pragma unroll
        for (int nf = 0; nf < 8; nf++) {
            int col = nf * 16 + cb;
#pragma unroll
            for (int j = 0; j < 4; j++)
                if (r0 + j < n_nodes)
                    O[(size_t)(r0 + j) * OUT_TOTAL + col] = f2bf(acc[rf][nf][j]);
        }
    }
}

// ---- CSR build: degree count ----
__global__ __launch_bounds__(256) void deg_kernel(
    const int* __restrict__ row, int* __restrict__ deg, int n_edges)
{
    int e = blockIdx.x * 256 + threadIdx.x;
    if (e < n_edges) atomicAdd(&deg[row[e]], 1);
}

// ---- scan phase A: per-block partial sums (coalesced) ----
__global__ __launch_bounds__(SCAN_T) void scan_part_kernel(
    const int* __restrict__ deg, int* __restrict__ part, int n)
{
    int i = blockIdx.x * SCAN_T + threadIdx.x;
    int v = (i < n) ? deg[i] : 0;
#pragma unroll
    for (int s = 1; s < 64; s <<= 1) v += __shfl_xor(v, s);
    __shared__ int wsum[SCAN_T / 64];
    if ((threadIdx.x & 63) == 0) wsum[threadIdx.x >> 6] = v;
    __syncthreads();
    if (threadIdx.x < SCAN_T / 64) {
        int s = wsum[threadIdx.x];
#pragma unroll
        for (int m = 1; m < SCAN_T / 64; m <<= 1) s += __shfl_xor(s, m);
        if (threadIdx.x == 0) part[blockIdx.x] = s;
    }
}

// ---- scan phase B+C: block prefix from part[], block-local exclusive scan ----
// requires gridDim.x <= 64 (n <= 65536)
__global__ __launch_bounds__(SCAN_T) void scan_write_kernel(
    const int* __restrict__ deg, const int* __restrict__ part,
    int* __restrict__ off, int n)
{
    __shared__ int bpre_s;
    if (threadIdx.x < 64) {
        int pv = ((int)threadIdx.x < (int)blockIdx.x) ? part[threadIdx.x] : 0;
#pragma unroll
        for (int s = 1; s < 64; s <<= 1) pv += __shfl_xor(pv, s);
        if (threadIdx.x == 0) bpre_s = pv;
    }

    int i = blockIdx.x * SCAN_T + threadIdx.x;
    int v = (i < n) ? deg[i] : 0;
    const int lane = threadIdx.x & 63, wid = threadIdx.x >> 6;

    // per-wave inclusive scan
    int incl = v;
#pragma unroll
    for (int s = 1; s < 64; s <<= 1) {
        int u = __shfl_up(incl, s);
        if (lane >= s) incl += u;
    }

    __shared__ int wsum[SCAN_T / 64];
    __shared__ int wpre[SCAN_T / 64];
    if (lane == 63) wsum[wid] = incl;
    __syncthreads();
    if (threadIdx.x < SCAN_T / 64) {
        int s = wsum[threadIdx.x];
        int ip = s;
#pragma unroll
        for (int st = 1; st < SCAN_T / 64; st <<= 1) {
            int u = __shfl_up(ip, st);
            if ((int)threadIdx.x >= st) ip += u;
        }
        wpre[threadIdx.x] = ip - s;   // exclusive wave prefix
    }
    __syncthreads();

    int excl = incl - v + wpre[wid] + bpre_s;
    if (i < n) off[i] = excl;
    if (i == n - 1) off[n] = excl + v;
}

// ---- CSR build: scatter col indices into buckets ----
__global__ __launch_bounds__(256) void fill_kernel(
    const int* __restrict__ row, const int* __restrict__ col,
    const int* __restrict__ off, int* __restrict__ cursor,
    int* __restrict__ csr_col, int n_edges)
{
    int e = blockIdx.x * 256 + threadIdx.x;
    if (e < n_edges) {
        int r = row[e];
        int pos = atomicAdd(&cursor[r], 1);
        csr_col[off[r] + pos] = col[e];
    }
}

// ---- fused per-node attention: one wave per node, bf16 Q/K/V ----
__global__ __launch_bounds__(256) void node_attn_kernel(
    const unsigned short* __restrict__ Qb, const unsigned short* __restrict__ Kb,
    const unsigned short* __restrict__ Vb,
    const int* __restrict__ off, const int* __restrict__ csr_col,
    float* __restrict__ out, int n_nodes)
{
    int wave = (blockIdx.x * 256 + threadIdx.x) >> 6;
    if (wave >= n_nodes) return;
    const int node = wave;
    const int lane = threadIdx.x & 63;
    const int h = lane & 3;
    const int slot = lane >> 2;

    const int e0 = off[node];
    const int deg = off[node + 1] - e0;

    bf16x8 qb[4];
    const bf16x8* qp = reinterpret_cast<const bf16x8*>(&Qb[(size_t)node * OUT_TOTAL + h * D_K]);
#pragma unroll
    for (int i = 0; i < 4; i++) qb[i] = qp[i];

    float m = NEG_BIG;
    float ssum = 0.f;
    float acc[D_K];
#pragma unroll
    for (int i = 0; i < D_K; i++) acc[i] = 0.f;

    int cn = -1;
    if (deg > 0) cn = (slot < deg) ? csr_col[e0 + slot] : -1;

    for (int base = 0; base < deg; base += 16) {
        int cn_cur = cn;
        int nbase = base + 16;
        if (nbase < deg) {
            int ni = nbase + slot;
            cn = (ni < deg) ? csr_col[e0 + ni] : -1;
        }
        bool act = (cn_cur >= 0);
        int cnc = act ? cn_cur : 0;

        const bf16x8* kp = reinterpret_cast<const bf16x8*>(&Kb[(size_t)cnc * OUT_TOTAL + h * D_K]);
        const bf16x8* vp = reinterpret_cast<const bf16x8*>(&Vb[(size_t)cnc * OUT_TOTAL + h * D_K]);
        bf16x8 kb[4], vb[4];
#pragma unroll
        for (int i = 0; i < 4; i++) kb[i] = kp[i];
#pragma unroll
        for (int i = 0; i < 4; i++) vb[i] = vp[i];

        float d = 0.f;
#pragma unroll
        for (int i = 0; i < 4; i++)
#pragma unroll
            for (int j = 0; j < 8; j++)
                d = fmaf(bf2f((unsigned short)kb[i][j]),
                         bf2f((unsigned short)qb[i][j]), d);

        float s = act ? d * 0.17677669529663689f : NEG_BIG;

        float cmax = s;
        cmax = fmaxf(cmax, __shfl_xor(cmax, 4));
        cmax = fmaxf(cmax, __shfl_xor(cmax, 8));
        cmax = fmaxf(cmax, __shfl_xor(cmax, 16));
        cmax = fmaxf(cmax, __shfl_xor(cmax, 32));

        // exact skip-rescale: only pay the O-wide pass when the max grew
        if (__any(cmax > m)) {
            float m_new = fmaxf(m, cmax);
            float scale = __expf(m - m_new);
            ssum *= scale;
#pragma unroll
            for (int i = 0; i < D_K; i++) acc[i] *= scale;
            m = m_new;
        }

        float wgt = act ? __expf(s - m) : 0.f;
        ssum += wgt;

#pragma unroll
        for (int i = 0; i < 4; i++)
#pragma unroll
            for (int j = 0; j < 8; j++)
                acc[i * 8 + j] = fmaf(wgt, bf2f((unsigned short)vb[i][j]), acc[i * 8 + j]);
    }

    // ssum: full butterfly (all lanes need it)
    ssum += __shfl_xor(ssum, 4);
    ssum += __shfl_xor(ssum, 8);
    ssum += __shfl_xor(ssum, 16);
    ssum += __shfl_xor(ssum, 32);

    // acc: reduce-scatter over the 16-lane head group (masks 32,16,8,4).
    float r16[16];
    {
        const int b = (lane >> 5) & 1;
#pragma unroll
        for (int j = 0; j < 16; j++) {
            float send = b ? acc[j] : acc[j + 16];
            float keep = b ? acc[j + 16] : acc[j];
            r16[j] = keep + __shfl_xor(send, 32);
        }
    }
    float r8[8];
    {
        const int b = (lane >> 4) & 1;
#pragma unroll
        for (int j = 0; j < 8; j++) {
            float send = b ? r16[j] : r16[j + 8];
            float keep = b ? r16[j + 8] : r16[j];
            r8[j] = keep + __shfl_xor(send, 16);
        }
    }
    float r4[4];
    {
        const int b = (lane >> 3) & 1;
#pragma unroll
        for (int j = 0; j < 4; j++) {
            float send = b ? r8[j] : r8[j + 4];
            float keep = b ? r8[j + 4] : r8[j];
            r4[j] = keep + __shfl_xor(send, 8);
        }
    }
    float r2[2];
    {
        const int b = (lane >> 2) & 1;
#pragma unroll
        for (int j = 0; j < 2; j++) {
            float send = b ? r4[j] : r4[j + 2];
            float keep = b ? r4[j + 2] : r4[j];
            r2[j] = keep + __shfl_xor(send, 4);
        }
    }

    float inv = (ssum > 0.f) ? 1.f / ssum : 0.f;
    float2 w2;
    w2.x = r2[0] * inv;
    w2.y = r2[1] * inv;
    *reinterpret_cast<float2*>(&out[(size_t)node * OUT_TOTAL + h * D_K + slot * 2]) = w2;
}

extern "C" void kernel_launch(void* const* d_in, const int* in_sizes, int n_in,
                              void* d_out, int out_size, void* d_ws, size_t ws_size,
                              hipStream_t stream)
{
    const float* x  = (const float*)d_in[0];
    const float* Wq = (const float*)d_in[1];
    const float* Wk = (const float*)d_in[2];
    const float* Wv = (const float*)d_in[3];
    const int*   ei = (const int*)d_in[4];
    float* out = (float*)d_out;

    const int n_nodes = in_sizes[0] / IN_FEAT;   // 50000
    const int n_edges = in_sizes[4] / 2;         // 800000
    const int* row = ei;
    const int* col = ei + n_edges;

    char* ws = (char*)d_ws;
    unsigned short* Q = (unsigned short*)ws;  ws += (size_t)n_nodes * OUT_TOTAL * sizeof(unsigned short);
    unsigned short* K = (unsigned short*)ws;  ws += (size_t)n_nodes * OUT_TOTAL * sizeof(unsigned short);
    unsigned short* V = (unsigned short*)ws;  ws += (size_t)n_nodes * OUT_TOTAL * sizeof(unsigned short);
    unsigned short* wt = (unsigned short*)ws; ws += (size_t)3 * OUT_TOTAL * IN_FEAT * sizeof(unsigned short);
    int* deg = (int*)ws;                      ws += (size_t)n_nodes * sizeof(int);
    int* off = (int*)ws;                      ws += (size_t)(n_nodes + 1) * sizeof(int);
    int* cursor = (int*)ws;                   ws += (size_t)n_nodes * sizeof(int);
    int* part = (int*)ws;                     ws += 64 * sizeof(int);
    int* csr_col = (int*)ws;                  ws += (size_t)n_edges * sizeof(int);

    (void)hipMemsetAsync(deg, 0, (size_t)n_nodes * sizeof(int), stream);
    (void)hipMemsetAsync(cursor, 0, (size_t)n_nodes * sizeof(int), stream);

    pack_w_kernel<<<(3 * OUT_TOTAL * IN_FEAT + 255) / 256, 256, 0, stream>>>(Wq, Wk, Wv, wt);

    int bpm = (n_nodes + PROJ_ROWS - 1) / PROJ_ROWS;
    proj_mfma_kernel<<<3 * bpm, 256, 0, stream>>>(x, wt, Q, K, V, n_nodes, bpm);

    int eb = (n_edges + 255) / 256;
    deg_kernel<<<eb, 256, 0, stream>>>(row, deg, n_edges);

    int sb = (n_nodes + SCAN_T - 1) / SCAN_T;   // 49 <= 64
    scan_part_kernel<<<sb, SCAN_T, 0, stream>>>(deg, part, n_nodes);
    scan_write_kernel<<<sb, SCAN_T, 0, stream>>>(deg, part, off, n_nodes);

    fill_kernel<<<eb, 256, 0, stream>>>(row, col, off, cursor, csr_col, n_edges);

    node_attn_kernel<<<(n_nodes + 3) / 4, 256, 0, stream>>>(Q, K, V, off, csr_col, out, n_nodes);
}